// Round 6
// baseline (296.773 us; speedup 1.0000x reference)
//
#include <hip/hip_runtime.h>
#include <stdint.h>

typedef unsigned long long u64;
typedef float f4 __attribute__((ext_vector_type(4)));   // clang vector: ok for
                                                        // __builtin_nontemporal_*

#define N_ANCH 100000
#define BATCH 8
#define NTGT 64
#define NFEAT 84
#define BLK 256
#define APL 2                         // anchors per lane
#define APB (BLK * APL)               // 512 anchors per block
#define NWAVE (BLK / 64)
#define NBX ((N_ANCH + APB - 1) / APB)   // 196 blocks per batch
#define GCHUNK (NFEAT / 4)            // 21 float4 per anchor row

// ---------------------------------------------------------------------------
// Fused kernel: IoU + masks + per-target partial argmax + assigned gather.
// Proven-exact skeleton (R2/R4): per-wave LDS boards, staggered-t =>
// conflict-free native ds_max_u64; outputs via nontemporal stores (written
// once, never re-read -> bypass L2 allocate).
// ---------------------------------------------------------------------------
__global__ __launch_bounds__(BLK) void fused_kernel(
    const float* __restrict__ labels,    // [B, NTGT, NFEAT]
    const float* __restrict__ anchors,   // [N_ANCH, 4] cxcywh
    float* __restrict__ out_fore,        // [B, N_ANCH]
    float* __restrict__ out_back,        // [B, N_ANCH]
    float* __restrict__ out_assigned,    // [B, N_ANCH, NFEAT]
    u64* __restrict__ ws_part)           // [B, NTGT, NBX]
{
#pragma clang fp contract(off)
    __shared__ float4 tbox[NTGT];                  // xyxy
    __shared__ u64 board[NWAVE][NTGT];             // per-wave winners
    __shared__ int sidx[APB];

    const int b    = blockIdx.y;
    const int bx   = blockIdx.x;
    const int tid  = threadIdx.x;
    const int wave = tid >> 6;

    if (tid < NTGT) {
        const float4 box = *(const float4*)(labels + ((size_t)b * NTGT + tid) * NFEAT);
        tbox[tid] = make_float4(box.x - box.z * 0.5f, box.y - box.w * 0.5f,
                                box.x + box.z * 0.5f, box.y + box.w * 0.5f);
    }
    ((u64*)board)[tid] = 0ull;                     // NWAVE*NTGT == BLK
    __syncthreads();

    const int n0 = bx * APB + tid;
    const int n1 = n0 + BLK;
    const bool v0 = (n0 < N_ANCH);
    const bool v1 = (n1 < N_ANCH);

    const float4 ab0 = *(const float4*)(anchors + (size_t)(v0 ? n0 : 0) * 4);
    const float4 ab1 = *(const float4*)(anchors + (size_t)(v1 ? n1 : 0) * 4);

    const float a0x1 = ab0.x - ab0.z * 0.5f, a0y1 = ab0.y - ab0.w * 0.5f;
    const float a0x2 = ab0.x + ab0.z * 0.5f, a0y2 = ab0.y + ab0.w * 0.5f;
    const float area0 = (a0x2 - a0x1) * (a0y2 - a0y1);
    const float a1x1 = ab1.x - ab1.z * 0.5f, a1y1 = ab1.y - ab1.w * 0.5f;
    const float a1x2 = ab1.x + ab1.z * 0.5f, a1y2 = ab1.y + ab1.w * 0.5f;
    const float area1 = (a1x2 - a1x1) * (a1y2 - a1y1);

    const u64 pn0 = (u64)(0xFFFFFFFFu - (uint32_t)n0);   // larger = smaller n
    const u64 pn1 = (u64)(0xFFFFFFFFu - (uint32_t)n1);

    u64 best0 = 0ull, best1 = 0ull;  // (iou_bits<<6)|(63-t): ties -> smallest t

    for (int s = 0; s < NTGT; ++s) {
        const int t = (tid + s) & (NTGT - 1);       // distinct t per lane in wave
        const float4 tb = tbox[t];                  // ds_read_b128
        const float areaB = (tb.z - tb.x) * (tb.w - tb.y);   // numpy op order

        // clip(min-max, 0) matches ref: lt=max, rb=min, wh=clip(rb-lt,0)
        const float w0 = fmaxf(fminf(a0x2, tb.z) - fmaxf(a0x1, tb.x), 0.0f);
        const float h0 = fmaxf(fminf(a0y2, tb.w) - fmaxf(a0y1, tb.y), 0.0f);
        const float inter0 = w0 * h0;
        const float iou0 = inter0 / (((area0 + areaB) - inter0) + 1e-9f);

        const float w1 = fmaxf(fminf(a1x2, tb.z) - fmaxf(a1x1, tb.x), 0.0f);
        const float h1 = fmaxf(fminf(a1y2, tb.w) - fmaxf(a1y1, tb.y), 0.0f);
        const float inter1 = w1 * h1;
        const float iou1 = inter1 / (((area1 + areaB) - inter1) + 1e-9f);

        const uint32_t ib0 = __float_as_uint(iou0); // iou >= 0: bits monotone
        const uint32_t ib1 = __float_as_uint(iou1);

        const u64 pa0 = ((u64)ib0 << 6) | (u64)(63 - t);
        const u64 pa1 = ((u64)ib1 << 6) | (u64)(63 - t);
        best0 = pa0 > best0 ? pa0 : best0;
        best1 = pa1 > best1 ? pa1 : best1;

        // merged candidate for this slot: packed max == (iou, then smaller n)
        const u64 c0 = v0 ? (((u64)ib0 << 32) | pn0) : 0ull;
        const u64 c1 = v1 ? (((u64)ib1 << 32) | pn1) : 0ull;
        const u64 c = c0 > c1 ? c0 : c1;
        atomicMax(&board[wave][t], c);              // native ds_max_u64, 1 slot/lane
    }

    if (v0) {
        const float mi = __uint_as_float((uint32_t)(best0 >> 6));
        const int   bt = 63 - (int)(best0 & 63u);
        const bool fore = (mi >= 0.5f);
        const bool back = (!fore) && (mi < 0.4f);
        const size_t o = (size_t)b * N_ANCH + n0;
        __builtin_nontemporal_store(fore ? 1.0f : 0.0f, out_fore + o);
        __builtin_nontemporal_store(back ? 1.0f : 0.0f, out_back + o);
        sidx[tid] = bt;
    } else {
        sidx[tid] = 0;
    }
    if (v1) {
        const float mi = __uint_as_float((uint32_t)(best1 >> 6));
        const int   bt = 63 - (int)(best1 & 63u);
        const bool fore = (mi >= 0.5f);
        const bool back = (!fore) && (mi < 0.4f);
        const size_t o = (size_t)b * N_ANCH + n1;
        __builtin_nontemporal_store(fore ? 1.0f : 0.0f, out_fore + o);
        __builtin_nontemporal_store(back ? 1.0f : 0.0f, out_back + o);
        sidx[tid + BLK] = bt;
    } else {
        sidx[tid + BLK] = 0;
    }
    __syncthreads();

    // merge 4 wave-boards -> one partial per (b,t,block); [b][t][blk] layout
    if (tid < NTGT) {
        const u64 m0 = board[0][tid];
        const u64 m1 = board[1][tid];
        const u64 m2 = board[2][tid];
        const u64 m3 = board[3][tid];
        const u64 a = m0 > m1 ? m0 : m1;
        const u64 c = m2 > m3 ? m2 : m3;
        ws_part[((size_t)b * NTGT + tid) * NBX + bx] = a > c ? a : c;
    }

    // gather epilogue: coalesced nontemporal float4 stores; labels L1-resident
    const float* lab_b = labels + (size_t)b * NTGT * NFEAT;
    float* out_b = out_assigned + ((size_t)b * N_ANCH + (size_t)bx * APB) * NFEAT;
    for (int i = tid; i < APB * GCHUNK; i += BLK) {      // 42 iterations
        const int nl = i / GCHUNK;
        const int k  = i - nl * GCHUNK;
        if (bx * APB + nl < N_ANCH) {
            const int t = sidx[nl];
            const f4 v = *(const f4*)(lab_b + (size_t)t * NFEAT + k * 4);
            __builtin_nontemporal_store(
                v, (f4*)(out_b + (size_t)nl * NFEAT + (size_t)k * 4));
        }
    }
}

// ---------------------------------------------------------------------------
// Fixup: one wave per (b,t); coalesced reads of [b][t][0..NBX); shuffle-max;
// scatter fore=1 / back=0 at best anchor (idempotent, replicates .at[].set).
// ---------------------------------------------------------------------------
__global__ __launch_bounds__(64) void fixup_kernel(
    const u64* __restrict__ ws_part,   // [B, NTGT, NBX]
    float* __restrict__ out_fore,
    float* __restrict__ out_back)
{
    const int bt   = blockIdx.x;     // 0..B*NTGT-1
    const int lane = threadIdx.x;    // 0..63
    const u64* p = ws_part + (size_t)bt * NBX;

    u64 best = 0ull;
    for (int i = lane; i < NBX; i += 64) {               // 4 coalesced rounds
        const u64 v = p[i];
        best = v > best ? v : best;
    }
    for (int off = 32; off > 0; off >>= 1) {
        const u64 o = __shfl_down(best, off, 64);
        best = o > best ? o : best;
    }
    if (lane == 0) {
        const uint32_t n = 0xFFFFFFFFu - (uint32_t)(best & 0xFFFFFFFFull);
        const int b = bt >> 6;
        const size_t o = (size_t)b * N_ANCH + n;
        out_fore[o] = 1.0f;
        out_back[o] = 0.0f;
    }
}

extern "C" void kernel_launch(void* const* d_in, const int* in_sizes, int n_in,
                              void* d_out, int out_size, void* d_ws, size_t ws_size,
                              hipStream_t stream) {
    const float* labels  = (const float*)d_in[0];   // (8, 64, 84) f32
    const float* anchors = (const float*)d_in[1];   // (1, 100000, 4) f32

    float* out_fore     = (float*)d_out;                         // B*N
    float* out_back     = out_fore + (size_t)BATCH * N_ANCH;     // B*N
    float* out_assigned = out_back + (size_t)BATCH * N_ANCH;     // B*N*84

    u64* ws_part = (u64*)d_ws;                                   // B*NTGT*NBX u64

    dim3 gridA(NBX, BATCH);
    fused_kernel<<<gridA, BLK, 0, stream>>>(labels, anchors, out_fore, out_back,
                                            out_assigned, ws_part);

    fixup_kernel<<<BATCH * NTGT, 64, 0, stream>>>(ws_part, out_fore, out_back);
}

// Round 7
// 291.086 us; speedup vs baseline: 1.0195x; 1.0195x over previous
//
#include <hip/hip_runtime.h>
#include <stdint.h>

typedef unsigned long long u64;

#define N_ANCH 100000
#define BATCH 8
#define NTGT 64
#define NFEAT 84
#define BLK 256
#define NWAVE (BLK / 64)
#define NBX ((N_ANCH + BLK - 1) / BLK)   // 391 blocks per batch
#define GCHUNK (NFEAT / 4)               // 21 float4 per anchor row

// ---------------------------------------------------------------------------
// Inner loop, templated on FULL (no boundary checks for 390/391 blocks).
// Packing is shift-free: candidate = {hi: iou_bits, lo: tiebreak} — a register
// pair, built for free. u64 max == (iou, then smaller t / smaller n).
// ---------------------------------------------------------------------------
template <bool FULL>
__device__ __forceinline__ void iou_loop(
    const int tid, const int wave, const int n, const bool valid,
    const float4* __restrict__ tbox, const float* __restrict__ sarea,
    u64* __restrict__ board, const float* __restrict__ anchors, u64& bestA)
{
#pragma clang fp contract(off)
    const int nld = FULL ? n : (valid ? n : 0);          // clamp only boundary
    const float4 ab = *(const float4*)(anchors + (size_t)nld * 4);
    const float ax1 = ab.x - ab.z * 0.5f;
    const float ay1 = ab.y - ab.w * 0.5f;
    const float ax2 = ab.x + ab.z * 0.5f;
    const float ay2 = ab.y + ab.w * 0.5f;
    const float areaA = (ax2 - ax1) * (ay2 - ay1);
    const u64 pn = (u64)(0xFFFFFFFFu - (uint32_t)n);     // larger = smaller n

    for (int s = 0; s < NTGT; ++s) {
        const int t = (tid + s) & (NTGT - 1);            // distinct t per lane
        const float4 tb = tbox[t];                       // ds_read_b128
        const float areaB = sarea[t];                    // staged, exact op order

        // lt=max, rb=min, wh=clip(rb-lt,0)  — matches reference op order
        const float w = fmaxf(fminf(ax2, tb.z) - fmaxf(ax1, tb.x), 0.0f);
        const float h = fmaxf(fminf(ay2, tb.w) - fmaxf(ay1, tb.y), 0.0f);
        const float inter = w * h;
        const float iou = inter / (((areaA + areaB) - inter) + 1e-9f);  // IEEE
        const uint32_t ib = __float_as_uint(iou);        // iou>=0: bits monotone

        // per-anchor argmax over t: {hi:ib, lo:63-t} (ties -> smallest t)
        const u64 pa = ((u64)ib << 32) | (u64)(63 - t);
        bestA = pa > bestA ? pa : bestA;

        // per-target board: {hi:ib, lo:~n} (ties -> smallest n);
        // per-wave board + staggered t => one lane per slot per instruction
        u64 c = ((u64)ib << 32) | pn;
        if (!FULL) c = valid ? c : 0ull;
        atomicMax(&board[(size_t)wave * NTGT + t], c);   // native ds_max_u64
    }
}

// ---------------------------------------------------------------------------
// Fused kernel: IoU + masks + per-target partial argmax + assigned gather.
// ---------------------------------------------------------------------------
__global__ __launch_bounds__(BLK) void fused_kernel(
    const float* __restrict__ labels,    // [B, NTGT, NFEAT]
    const float* __restrict__ anchors,   // [N_ANCH, 4] cxcywh
    float* __restrict__ out_fore,        // [B, N_ANCH]
    float* __restrict__ out_back,        // [B, N_ANCH]
    float* __restrict__ out_assigned,    // [B, N_ANCH, NFEAT]
    u64* __restrict__ ws_part)           // [B, NTGT, NBX]
{
#pragma clang fp contract(off)
    __shared__ float4 tbox[NTGT];                 // xyxy
    __shared__ float sarea[NTGT];
    __shared__ u64 board[NWAVE * NTGT];           // per-wave winners
    __shared__ int sidx[BLK];

    const int b    = blockIdx.y;
    const int bx   = blockIdx.x;
    const int tid  = threadIdx.x;
    const int wave = tid >> 6;

    if (tid < NTGT) {
        const float4 box = *(const float4*)(labels + ((size_t)b * NTGT + tid) * NFEAT);
        const float x1 = box.x - box.z * 0.5f;
        const float y1 = box.y - box.w * 0.5f;
        const float x2 = box.x + box.z * 0.5f;
        const float y2 = box.y + box.w * 0.5f;
        tbox[tid] = make_float4(x1, y1, x2, y2);
        sarea[tid] = (x2 - x1) * (y2 - y1);       // numpy op order
    }
    board[tid] = 0ull;                            // NWAVE*NTGT == BLK
    __syncthreads();

    const int n = bx * BLK + tid;
    u64 bestA = 0ull;
    bool valid = true;
    if (bx != NBX - 1) {                          // uniform branch: peeled main path
        iou_loop<true>(tid, wave, n, true, tbox, sarea, board, anchors, bestA);
    } else {
        valid = (n < N_ANCH);
        iou_loop<false>(tid, wave, n, valid, tbox, sarea, board, anchors, bestA);
    }

    if (valid) {
        const float mi = __uint_as_float((uint32_t)(bestA >> 32));
        const int   bt = 63 - (int)(bestA & 0xFFFFFFFFull);
        const bool fore = (mi >= 0.5f);
        const bool back = (!fore) && (mi < 0.4f);
        const size_t o = (size_t)b * N_ANCH + n;
        out_fore[o] = fore ? 1.0f : 0.0f;
        out_back[o] = back ? 1.0f : 0.0f;
        sidx[tid] = bt;
    } else {
        sidx[tid] = 0;
    }
    __syncthreads();

    // merge 4 wave-boards -> one partial per (b,t,block); [b][t][blk] layout
    if (tid < NTGT) {
        const u64 m0 = board[tid];
        const u64 m1 = board[NTGT + tid];
        const u64 m2 = board[2 * NTGT + tid];
        const u64 m3 = board[3 * NTGT + tid];
        const u64 a = m0 > m1 ? m0 : m1;
        const u64 c = m2 > m3 ? m2 : m3;
        ws_part[((size_t)b * NTGT + tid) * NBX + bx] = a > c ? a : c;
    }

    // gather epilogue: coalesced float4 stores; labels rows are L1-resident
    const float* lab_b = labels + (size_t)b * NTGT * NFEAT;
    float* out_b = out_assigned + ((size_t)b * N_ANCH + (size_t)bx * BLK) * NFEAT;
    for (int i = tid; i < BLK * GCHUNK; i += BLK) {      // 21 iterations
        const int nl = i / GCHUNK;
        const int k  = i - nl * GCHUNK;
        if (bx * BLK + nl < N_ANCH) {
            const int t = sidx[nl];
            const float4 v = *(const float4*)(lab_b + (size_t)t * NFEAT + k * 4);
            *(float4*)(out_b + (size_t)nl * NFEAT + (size_t)k * 4) = v;
        }
    }
}

// ---------------------------------------------------------------------------
// Fixup: one wave per (b,t); coalesced reads of [b][t][0..NBX); shuffle-max;
// scatter fore=1 / back=0 at best anchor (idempotent, replicates .at[].set).
// ---------------------------------------------------------------------------
__global__ __launch_bounds__(64) void fixup_kernel(
    const u64* __restrict__ ws_part,   // [B, NTGT, NBX]
    float* __restrict__ out_fore,
    float* __restrict__ out_back)
{
    const int bt   = blockIdx.x;     // 0..B*NTGT-1
    const int lane = threadIdx.x;    // 0..63
    const u64* p = ws_part + (size_t)bt * NBX;

    u64 best = 0ull;
    for (int i = lane; i < NBX; i += 64) {               // 7 coalesced rounds
        const u64 v = p[i];
        best = v > best ? v : best;
    }
    for (int off = 32; off > 0; off >>= 1) {
        const u64 o = __shfl_down(best, off, 64);
        best = o > best ? o : best;
    }
    if (lane == 0) {
        const uint32_t n = 0xFFFFFFFFu - (uint32_t)(best & 0xFFFFFFFFull);
        const int b = bt >> 6;
        const size_t o = (size_t)b * N_ANCH + n;
        out_fore[o] = 1.0f;
        out_back[o] = 0.0f;
    }
}

extern "C" void kernel_launch(void* const* d_in, const int* in_sizes, int n_in,
                              void* d_out, int out_size, void* d_ws, size_t ws_size,
                              hipStream_t stream) {
    const float* labels  = (const float*)d_in[0];   // (8, 64, 84) f32
    const float* anchors = (const float*)d_in[1];   // (1, 100000, 4) f32

    float* out_fore     = (float*)d_out;                         // B*N
    float* out_back     = out_fore + (size_t)BATCH * N_ANCH;     // B*N
    float* out_assigned = out_back + (size_t)BATCH * N_ANCH;     // B*N*84

    u64* ws_part = (u64*)d_ws;                                   // B*NTGT*NBX u64

    dim3 gridA(NBX, BATCH);
    fused_kernel<<<gridA, BLK, 0, stream>>>(labels, anchors, out_fore, out_back,
                                            out_assigned, ws_part);

    fixup_kernel<<<BATCH * NTGT, 64, 0, stream>>>(ws_part, out_fore, out_back);
}